// Round 4
// baseline (78.652 us; speedup 1.0000x reference)
//
#include <hip/hip_runtime.h>

#define B_N 256
#define B_C 256
#define MID 128
#define NELEM (B_N * B_C)
#define DEPTH 4

typedef float f32x4 __attribute__((ext_vector_type(4)));
typedef __bf16 bf16x8 __attribute__((ext_vector_type(8)));
typedef short short8 __attribute__((ext_vector_type(8)));

__device__ __forceinline__ float bf2f(unsigned short h) {
  return __builtin_bit_cast(float, (unsigned int)h << 16);
}

// native casts -> v_cvt_pk_bf16_f32 (RTNE)
__device__ __forceinline__ short8 cvt8(float4 a, float4 b) {
  union { unsigned short us[8]; short8 v; } P;
  P.us[0] = __builtin_bit_cast(unsigned short, (__bf16)a.x);
  P.us[1] = __builtin_bit_cast(unsigned short, (__bf16)a.y);
  P.us[2] = __builtin_bit_cast(unsigned short, (__bf16)a.z);
  P.us[3] = __builtin_bit_cast(unsigned short, (__bf16)a.w);
  P.us[4] = __builtin_bit_cast(unsigned short, (__bf16)b.x);
  P.us[5] = __builtin_bit_cast(unsigned short, (__bf16)b.y);
  P.us[6] = __builtin_bit_cast(unsigned short, (__bf16)b.z);
  P.us[7] = __builtin_bit_cast(unsigned short, (__bf16)b.w);
  return P.v;
}

// swizzled LDS element offset for the 8-element chunk (i, tid)
__device__ __forceinline__ int xs_off(int i, int tid) {
  const int e8 = i * 4096 + tid * 8;
  const int r = e8 >> 8;
  const int q = (e8 >> 3) & 31;
  return (r << 8) + ((q ^ (r & 7)) << 3);
}

// one output row-chunk: read LDS, scale by wexp[row], nt-store to out
__device__ __forceinline__ void out_row(
    const unsigned short* __restrict__ Xs, const float* __restrict__ wexp,
    float* __restrict__ ob, int i, int tid)
{
  const int e8 = i * 4096 + tid * 8;
  union { short8 v; unsigned short us[8]; } P;
  P.v = *reinterpret_cast<const short8*>(&Xs[xs_off(i, tid)]);
  const float wt = wexp[e8 >> 8];
  f32x4 o0, o1;
  o0[0] = bf2f(P.us[0]) * wt; o0[1] = bf2f(P.us[1]) * wt;
  o0[2] = bf2f(P.us[2]) * wt; o0[3] = bf2f(P.us[3]) * wt;
  o1[0] = bf2f(P.us[4]) * wt; o1[1] = bf2f(P.us[5]) * wt;
  o1[2] = bf2f(P.us[6]) * wt; o1[3] = bf2f(P.us[7]) * wt;
  __builtin_nontemporal_store(o0, reinterpret_cast<f32x4*>(ob + e8));
  __builtin_nontemporal_store(o1, reinterpret_cast<f32x4*>(ob + e8 + 4));
}

// Split-pass compute: sim rows in two halves, acc = 64 regs instead of 128.
// Reductions (all linear over rows, using exact symmetry of sim):
//   rp[n]  = sum_m sim[m,n]^2
//   u~[n]  = sum_m sim[m,n] * smid[m] * kern[m],  smid[m] = sim[m,MID]
// smid for each pass's rows is held by wave 4 (col MID: 32w+lr==128 -> w=4,lr=0),
// D-layout row = 16t + 4g + reg.
// logits: w[n] = u~[n] * rinv[n] * rinv[MID] + bias[n].
__device__ __forceinline__ void compute_batch(
    const unsigned short* __restrict__ Xs, float* smid_s, float* r2s,
    float* wlog, float* wexp, const float* kern_s,
    const float* __restrict__ bias, int tid)
{
  const int w  = tid >> 6;
  const int l  = tid & 63;
  const int lr = l & 15;
  const int g  = l >> 4;
  const int sw = lr & 7;
  const int rb0 = 32 * w + lr;
  const int rb1 = rb0 + 16;

  float rp0 = 0.f, rp1 = 0.f, up0 = 0.f, up1 = 0.f;

  #pragma unroll
  for (int p = 0; p < 2; ++p) {
    f32x4 acc[8][2];
    #pragma unroll
    for (int tt = 0; tt < 8; ++tt) {
      acc[tt][0] = {0.f, 0.f, 0.f, 0.f};
      acc[tt][1] = {0.f, 0.f, 0.f, 0.f};
    }
    #pragma unroll
    for (int kk = 0; kk < 8; ++kk) {
      const int qs = (((4 * kk + g) ^ sw) << 3);
      const bf16x8 bf0 = __builtin_bit_cast(bf16x8,
          *reinterpret_cast<const short8*>(&Xs[(rb0 << 8) + qs]));
      const bf16x8 bf1 = __builtin_bit_cast(bf16x8,
          *reinterpret_cast<const short8*>(&Xs[(rb1 << 8) + qs]));
      #pragma unroll
      for (int tt = 0; tt < 8; ++tt) {
        const int row = 16 * (8 * p + tt) + lr;
        const bf16x8 af = __builtin_bit_cast(bf16x8,
            *reinterpret_cast<const short8*>(&Xs[(row << 8) + qs]));
        acc[tt][0] = __builtin_amdgcn_mfma_f32_16x16x32_bf16(af, bf0, acc[tt][0], 0, 0, 0);
        acc[tt][1] = __builtin_amdgcn_mfma_f32_16x16x32_bf16(af, bf1, acc[tt][1], 0, 0, 0);
      }
    }
    // squares (rows of this pass)
    #pragma unroll
    for (int tt = 0; tt < 8; ++tt) {
      #pragma unroll
      for (int r = 0; r < 4; ++r) {
        rp0 += acc[tt][0][r] * acc[tt][0][r];
        rp1 += acc[tt][1][r] * acc[tt][1][r];
      }
    }
    // column-MID extraction: wave 4, lanes lr==0 hold sim[m,128]
    if (w == 4 && lr == 0) {
      #pragma unroll
      for (int tt = 0; tt < 8; ++tt) {
        #pragma unroll
        for (int r = 0; r < 4; ++r)
          smid_s[128 * p + 16 * tt + 4 * g + r] = acc[tt][0][r];
      }
    }
    __syncthreads();
    // u~ accumulation for this pass's rows
    #pragma unroll
    for (int tt = 0; tt < 8; ++tt) {
      #pragma unroll
      for (int r = 0; r < 4; ++r) {
        const int m = 128 * p + 16 * tt + 4 * g + r;
        const float y = smid_s[m] * kern_s[m];
        up0 += acc[tt][0][r] * y;
        up1 += acc[tt][1][r] * y;
      }
    }
  }

  rp0 += __shfl_xor(rp0, 16); rp0 += __shfl_xor(rp0, 32);
  rp1 += __shfl_xor(rp1, 16); rp1 += __shfl_xor(rp1, 32);
  up0 += __shfl_xor(up0, 16); up0 += __shfl_xor(up0, 32);
  up1 += __shfl_xor(up1, 16); up1 += __shfl_xor(up1, 32);
  if (l < 16) {
    r2s[32 * w + l]       = rp0;
    r2s[32 * w + 16 + l]  = rp1;
    wlog[32 * w + l]      = up0;   // u~ stored, scaled below
    wlog[32 * w + 16 + l] = up1;
  }
  __syncthreads();

  if (tid < B_N) {
    const float rinvm = rsqrtf(fmaxf(r2s[MID], 1e-12f));
    wlog[tid] = wlog[tid] * rsqrtf(fmaxf(r2s[tid], 1e-12f)) * rinvm + bias[tid];
  }
  __syncthreads();

  if (tid < 64) {
    const float a0 = wlog[tid], a1 = wlog[tid + 64], a2 = wlog[tid + 128], a3 = wlog[tid + 192];
    float mx = fmaxf(fmaxf(a0, a1), fmaxf(a2, a3));
    #pragma unroll
    for (int off = 32; off >= 1; off >>= 1) mx = fmaxf(mx, __shfl_xor(mx, off));
    const float e0 = __expf(a0 - mx), e1 = __expf(a1 - mx), e2 = __expf(a2 - mx), e3 = __expf(a3 - mx);
    float s = e0 + e1 + e2 + e3;
    #pragma unroll
    for (int off = 32; off >= 1; off >>= 1) s += __shfl_xor(s, off);
    const float inv = 1.0f / s;
    wexp[tid] = e0 * inv; wexp[tid + 64] = e1 * inv;
    wexp[tid + 128] = e2 * inv; wexp[tid + 192] = e3 * inv;
  }
  __syncthreads();
}

// Persistent: 256 blocks x 2 batches. Merged phase overlaps W(b0) with R(b1):
// wave w only touches rows {16i+2w, 16i+2w+1} in out/fill paths -> disjoint
// across waves -> refill own rows right after reading them, no barrier.
__global__ __launch_bounds__(512, 2) void spat_attn(
    const float* __restrict__ x, const float* __restrict__ kern,
    const float* __restrict__ bias, float* __restrict__ out, int nb)
{
  __shared__ __align__(16) unsigned short Xs[NELEM];  // 128 KB swizzled bf16
  __shared__ float smid_s[B_N];
  __shared__ float r2s[B_N];
  __shared__ float wlog[B_N];
  __shared__ float wexp[B_N];
  __shared__ float kern_s[B_N];

  const int tid = threadIdx.x;
  const int b0 = blockIdx.x;
  const int b1 = blockIdx.x + gridDim.x;

  if (tid < B_N) kern_s[tid] = kern[tid];

  // ---- R0: load b0 -> cvt -> swizzled LDS ----
  {
    const float* __restrict__ xb = x + (size_t)b0 * NELEM;
    #pragma unroll 4
    for (int i = 0; i < 16; ++i) {
      const float4 f0 = *reinterpret_cast<const float4*>(xb + i * 4096 + tid * 8);
      const float4 f1 = *reinterpret_cast<const float4*>(xb + i * 4096 + tid * 8 + 4);
      *reinterpret_cast<short8*>(&Xs[xs_off(i, tid)]) = cvt8(f0, f1);
    }
  }
  __syncthreads();

  // ---- C0 ----
  compute_batch(Xs, smid_s, r2s, wlog, wexp, kern_s, bias, tid);

  // ---- Merged: W(b0) || R(b1), per-wave row ownership, depth-4 pipeline ----
  float* __restrict__ ob0 = out + (size_t)b0 * NELEM;
  if (b1 < nb) {
    const float* __restrict__ xb1 = x + (size_t)b1 * NELEM;
    float4 pf[2 * DEPTH];
    #pragma unroll
    for (int j = 0; j < DEPTH; ++j) {
      pf[2 * j]     = *reinterpret_cast<const float4*>(xb1 + j * 4096 + tid * 8);
      pf[2 * j + 1] = *reinterpret_cast<const float4*>(xb1 + j * 4096 + tid * 8 + 4);
    }
    #pragma unroll
    for (int i = 0; i < 16; ++i) {
      out_row(Xs, wexp, ob0, i, tid);             // read own LDS rows (b0)
      const int s = i & (DEPTH - 1);
      *reinterpret_cast<short8*>(&Xs[xs_off(i, tid)]) = cvt8(pf[2 * s], pf[2 * s + 1]);
      if (i + DEPTH < 16) {
        pf[2 * s]     = *reinterpret_cast<const float4*>(xb1 + (i + DEPTH) * 4096 + tid * 8);
        pf[2 * s + 1] = *reinterpret_cast<const float4*>(xb1 + (i + DEPTH) * 4096 + tid * 8 + 4);
      }
    }
    __syncthreads();   // all rows of b1 in LDS

    // ---- C1 + W1 ----
    compute_batch(Xs, smid_s, r2s, wlog, wexp, kern_s, bias, tid);
    float* __restrict__ ob1 = out + (size_t)b1 * NELEM;
    #pragma unroll 4
    for (int i = 0; i < 16; ++i) out_row(Xs, wexp, ob1, i, tid);
  } else {
    #pragma unroll 4
    for (int i = 0; i < 16; ++i) out_row(Xs, wexp, ob0, i, tid);
  }
}

extern "C" void kernel_launch(void* const* d_in, const int* in_sizes, int n_in,
                              void* d_out, int out_size, void* d_ws, size_t ws_size,
                              hipStream_t stream) {
  const float* x    = (const float*)d_in[0];
  const float* kern = (const float*)d_in[1];
  const float* bias = (const float*)d_in[2];
  float* out = (float*)d_out;
  const int nb = in_sizes[0] / NELEM;          // 512 batches
  const int grid = (nb + 1) / 2;               // 256 persistent blocks
  spat_attn<<<dim3(grid), dim3(512), 0, stream>>>(x, kern, bias, out, nb);
}